// Round 7
// baseline (30997.101 us; speedup 1.0000x reference)
//
#include <hip/hip_runtime.h>
#include <math.h>

#define HWN 4096
#define Bn 4
#define Tn 8
#define ROW 66
#define PXP 4356                       // 66*66 padded pixel space

#define SxP  ((long)Bn*PXP*32)         // per-plane elems, padded C=32 tensor
#define S64P ((long)Bn*PXP*64)         // per-plane elems, padded C=64 tensor
#define S64u ((long)Bn*HWN*64)         // fp32 unpadded tensor elems

typedef __attribute__((ext_vector_type(4))) _Float16 f16x4;
typedef __attribute__((ext_vector_type(8))) _Float16 f16x8;
typedef __attribute__((ext_vector_type(4))) float floatx4;

__device__ __forceinline__ float sigmoidf_(float v) { return 1.f / (1.f + expf(-v)); }

__device__ __forceinline__ void split8(const float* vv, f16x8* hi, f16x8* lo) {
#pragma unroll
    for (int j = 0; j < 8; ++j) {
        _Float16 h = (_Float16)vv[j];
        (*hi)[j] = h;
        (*lo)[j] = (_Float16)(vv[j] - (float)h);
    }
}
__device__ __forceinline__ void split_st4(_Float16* p, long ps, const float* v) {
    _Float16 a = (_Float16)v[0], b = (_Float16)v[1], c = (_Float16)v[2], d = (_Float16)v[3];
    f16x4 hv = {a, b, c, d};
    f16x4 lv = {(_Float16)(v[0] - (float)a), (_Float16)(v[1] - (float)b),
                (_Float16)(v[2] - (float)c), (_Float16)(v[3] - (float)d)};
    *(f16x4*)p = hv; *(f16x4*)(p + ps) = lv;
}
__device__ __forceinline__ void rec4(const _Float16* p, long ps, float* o) {
    f16x4 h = *(const f16x4*)p, l = *(const f16x4*)(p + ps);
#pragma unroll
    for (int j = 0; j < 4; ++j) o[j] = (float)h[j] + (float)l[j];
}

// ---------------------------------------------------------------------------
// Weight prep: fp32 [Cout][Ctot][KK] -> A-frag-swizzled split-f16
// [plane][kk][chunk][cog][lane][j]. K-order: in1 channels padded to C1p, then
// in2 channels. A-frag (16x16x32): A[m=lane&15][k=(lane>>4)*8+j].
// ---------------------------------------------------------------------------
__global__ __launch_bounds__(256) void prep_w_kernel(
    const float* __restrict__ W, _Float16* __restrict__ dst,
    int Ctot, int C1, int C1p, int Cout, int nch, int KK)
{
    const int nch1 = C1p >> 5;
    const int ncog = Cout >> 4;
    const long total = (long)KK * nch * ncog * 512;
    for (long i = (long)blockIdx.x * 256 + threadIdx.x; i < total;
         i += (long)gridDim.x * 256) {
        int j    = (int)(i & 7);
        int lane = (int)((i >> 3) & 63);
        long r   = i >> 9;
        int f = (int)(r % ncog); r /= ncog;
        int c = (int)(r % nch);  r /= nch;
        int kk = (int)r;
        int co  = f * 16 + (lane & 15);
        int cil = c * 32 + (lane >> 4) * 8 + j;
        int ci;
        if (c < nch1) ci = (cil < C1) ? cil : -1;
        else { int t2 = C1 + (cil - C1p); ci = (t2 < Ctot) ? t2 : -1; }
        float v = (ci >= 0) ? W[((long)co * Ctot + ci) * KK + kk] : 0.f;
        _Float16 hi = (_Float16)v;
        dst[i]         = hi;
        dst[total + i] = (_Float16)(v - (float)hi);
    }
}

// x fp32 [b][t][16][4096] -> x_cl split-f16 padded [t][plane][b][pxP][32]
__global__ __launch_bounds__(256) void prep_x_kernel(
    const float* __restrict__ x, _Float16* __restrict__ xcl)
{
    const int i = blockIdx.x * 256 + threadIdx.x;     // 131072 total
    const int px = i & 4095;
    const int t  = (i >> 12) & 7;
    const int b  = i >> 15;
    const int y = px >> 6, xx = px & 63;
    const long pxP = (long)(y + 1) * ROW + xx + 1;
    f16x8 h0v, h1v, l0v, l1v;
#pragma unroll
    for (int ch = 0; ch < 8; ++ch) {
        float v = x[((long)(b * 8 + t) * 16 + ch) * HWN + px];
        _Float16 h = (_Float16)v; h0v[ch] = h; l0v[ch] = (_Float16)(v - (float)h);
    }
#pragma unroll
    for (int ch = 0; ch < 8; ++ch) {
        float v = x[((long)(b * 8 + t) * 16 + ch + 8) * HWN + px];
        _Float16 h = (_Float16)v; h1v[ch] = h; l1v[ch] = (_Float16)(v - (float)h);
    }
    _Float16* d = xcl + (long)t * 2 * SxP + ((long)b * PXP + pxP) * 32;
    *(f16x8*)d = h0v; *(f16x8*)(d + 8) = h1v;
    *(f16x8*)(d + SxP) = l0v; *(f16x8*)(d + SxP + 8) = l1v;
}

// ---------------------------------------------------------------------------
// MFMA implicit-GEMM 3x3 conv, NO LDS: B-frags loaded directly from padded
// split-f16 channels-last global tensors (zero borders -> no bounds logic).
// K-order: in1 chunks (nch1) then in2 chunks. Weight frags double-buffered.
// EPI=0: plain conv, merged A/B dispatch (which = blockIdx.y >= nA), split out.
// EPI=1 (NF=1): H-conv: tanh + state update (+ q/k on last cell);
//   which=0: gc branch, state c fp32 unpadded; which=1: gm, m split padded.
// Block 256 = 4 waves; tile M=NF*16 couts x N=256 px (16x16 spatial).
// ---------------------------------------------------------------------------
template<int EPI, int NF>
__global__ __launch_bounds__(256) void conv3m(
    const _Float16* __restrict__ in1, int C1p, long ps1,
    const _Float16* __restrict__ in2a, const _Float16* __restrict__ in2b, long ps2,
    int nch1, int nch,
    const _Float16* __restrict__ wA, const float* __restrict__ biasA,
    _Float16* outA, int CoutA, int ncogA,
    const _Float16* __restrict__ wB, const float* __restrict__ biasB,
    _Float16* outB, int CoutB, int ncogB, int nA,
    const float* __restrict__ zA, const float* __restrict__ zB,
    const float* __restrict__ cst, const _Float16* __restrict__ mst,
    float* cnew, _Float16* mnew,
    const float* __restrict__ rten, const float* __restrict__ xrten,
    float* qout, float* kout, int last)
{
    const int tid = threadIdx.x;
    const int tyP = (blockIdx.x >> 2) * 16;
    const int txP = (blockIdx.x & 3) * 16;
    const int b   = blockIdx.z & 3;
    const int which = (EPI == 1) ? (int)(blockIdx.z >> 2)
                                 : (blockIdx.y >= (unsigned)nA ? 1 : 0);

    const _Float16* in2  = which ? in2b : in2a;
    const _Float16* Wf   = which ? wB : wA;
    const float*    bias = which ? biasB : biasA;
    const int Cout = which ? CoutB : CoutA;
    const int ncog = which ? ncogB : ncogA;
    const int cog0 = (EPI == 1) ? blockIdx.y * NF
                   : (which ? (blockIdx.y - nA) * NF : blockIdx.y * NF);
    const int co0  = cog0 * 16;

    const int lane = tid & 63, wv = tid >> 6, tl = lane & 15, quad = lane >> 4;
    const long wplane = (long)9 * nch * ncog * 512;

    floatx4 acc[NF][4];
#pragma unroll
    for (int f = 0; f < NF; ++f)
#pragma unroll
        for (int g = 0; g < 4; ++g) acc[f][g] = (floatx4){0.f, 0.f, 0.f, 0.f};

    // weight double-buffer: cur = (c+kk)&1
    f16x8 wh[2][NF], wl[2][NF];
    {
        const long wo = ((long)0 * ncog + cog0) * 512 + lane * 8;
#pragma unroll
        for (int f = 0; f < NF; ++f) {
            wh[0][f] = *(const f16x8*)(Wf + wo + (long)f * 512);
            wl[0][f] = *(const f16x8*)(Wf + wplane + wo + (long)f * 512);
        }
    }

    for (int c = 0; c < nch; ++c) {
        const _Float16* pT; long PS; int Cc, cb;
        if (c < nch1) { pT = in1; PS = ps1; Cc = C1p; cb = c * 32; }
        else          { pT = in2; PS = ps2; Cc = 64;  cb = (c - nch1) * 32; }
        const _Float16* pTb = pT + (long)b * PXP * Cc;
#pragma unroll
        for (int kk = 0; kk < 9; ++kk) {
            const int cur = (c + kk) & 1;
            // prefetch next weight frags
            int nc = c, nk = kk + 1;
            if (nk == 9) { nk = 0; nc = c + 1; }
            if (nc < nch) {
                const long wo = ((long)(nk * nch + nc) * ncog + cog0) * 512 + lane * 8;
#pragma unroll
                for (int f = 0; f < NF; ++f) {
                    wh[cur ^ 1][f] = *(const f16x8*)(Wf + wo + (long)f * 512);
                    wl[cur ^ 1][f] = *(const f16x8*)(Wf + wplane + wo + (long)f * 512);
                }
            }
            const int ky = kk / 3, kx = kk - ky * 3;
            f16x8 bh[4], bl[4];
#pragma unroll
            for (int g = 0; g < 4; ++g) {
                const long o = ((long)(tyP + wv * 4 + g + ky) * ROW + (txP + tl + kx)) * Cc
                             + cb + quad * 8;
                bh[g] = *(const f16x8*)(pTb + o);
                bl[g] = *(const f16x8*)(pTb + PS + o);
            }
#pragma unroll
            for (int f = 0; f < NF; ++f)
#pragma unroll
                for (int g = 0; g < 4; ++g) {
                    acc[f][g] = __builtin_amdgcn_mfma_f32_16x16x32_f16(wh[cur][f], bh[g], acc[f][g], 0, 0, 0);
                    acc[f][g] = __builtin_amdgcn_mfma_f32_16x16x32_f16(wh[cur][f], bl[g], acc[f][g], 0, 0, 0);
                    acc[f][g] = __builtin_amdgcn_mfma_f32_16x16x32_f16(wl[cur][f], bh[g], acc[f][g], 0, 0, 0);
                }
        }
    }

    // epilogue: C/D layout col(px)=lane&15, row(co)=quad*4+reg
    if (EPI == 0) {
        _Float16* outp = which ? outB : outA;
        const long pso = (long)Bn * HWN * Cout;
#pragma unroll
        for (int f = 0; f < NF; ++f) {
            const int co = co0 + f * 16 + quad * 4;
#pragma unroll
            for (int g = 0; g < 4; ++g) {
                const long px = (long)(tyP + wv * 4 + g) * 64 + txP + tl;
                float v[4];
#pragma unroll
                for (int r = 0; r < 4; ++r) v[r] = acc[f][g][r] + bias[co + r];
                split_st4(outp + ((long)b * HWN + px) * Cout + co, pso, v);
            }
        }
    } else {
        const float* zt = which ? zB : zA;
        float* qk = which ? kout : qout;
        const int co = co0 + quad * 4;
#pragma unroll
        for (int g = 0; g < 4; ++g) {
            const int py = tyP + wv * 4 + g, pxx = txP + tl;
            const long px   = (long)py * 64 + pxx;
            const long offU = ((long)b * HWN + px) * 64 + co;
            const long offP = ((long)b * PXP + (long)(py + 1) * ROW + pxx + 1) * 64 + co;
            float4 zv4 = *(const float4*)(zt + offU);
            const float* zp = (const float*)&zv4;
            float sv[4];
            if (which) rec4(mst + offP, S64P, sv);
            else { float4 t4 = *(const float4*)(cst + offU);
                   sv[0] = t4.x; sv[1] = t4.y; sv[2] = t4.z; sv[3] = t4.w; }
            float gv[4], cn[4];
#pragma unroll
            for (int r = 0; r < 4; ++r) {
                gv[r] = tanhf(acc[0][g][r] + bias[co + r]);
                cn[r] = zp[r] * sv[r] + (1.f - zp[r]) * gv[r];
            }
            if (which) split_st4(mnew + offP, S64P, cn);
            else *(float4*)(cnew + offU) = *(float4*)cn;
            if (last) {
                float4 rv = *(const float4*)(rten + offU);
                float4 xv = *(const float4*)(xrten + offU);
                const float* rp = (const float*)&rv;
                const float* xp = (const float*)&xv;
#pragma unroll
                for (int r = 0; r < 4; ++r)
                    qk[((long)(b * 64) + co + r) * HWN + px] =
                        0.25f * (rp[r] + xp[r] + cn[r] + gv[r]);
            }
        }
    }
}

// ---------------------------------------------------------------------------
// 1x1 conv (MFMA) over concat([c fp32-unpadded, m split-padded]):
// h = o * tanh(conv + bias), stored split-padded. grid (64, B), wave=16px x 64co.
// ---------------------------------------------------------------------------
__global__ __launch_bounds__(256) void conv1x1m(
    const float* __restrict__ cten, const _Float16* __restrict__ mten,
    const float* __restrict__ oten,
    const _Float16* __restrict__ W, const float* __restrict__ bias,
    _Float16* houtp)
{
    const int tid = threadIdx.x;
    const int lane = tid & 63, wv = tid >> 6, tl = lane & 15, quad = lane >> 4;
    const int b = blockIdx.y;
    const int px = blockIdx.x * 64 + wv * 16 + tl;
    const int y = px >> 6, xx = px & 63;
    const long pxP = (long)(y + 1) * ROW + xx + 1;
    const long offU = ((long)b * HWN + px) * 64;
    const long offP = ((long)b * PXP + pxP) * 64;

    f16x8 wh[4][4], wl[4][4];
#pragma unroll
    for (int c = 0; c < 4; ++c)
#pragma unroll
        for (int f = 0; f < 4; ++f) {
            const long wo = (long)(c * 4 + f) * 512 + lane * 8;
            wh[c][f] = *(const f16x8*)(W + wo);
            wl[c][f] = *(const f16x8*)(W + 8192 + wo);
        }
    f16x8 bh[4], bl[4];
#pragma unroll
    for (int c = 0; c < 2; ++c) {           // c-state fp32 -> split in reg
        const int ch0 = c * 32 + quad * 8;
        float4 p0 = *(const float4*)(cten + offU + ch0);
        float4 p1 = *(const float4*)(cten + offU + ch0 + 4);
        float vv[8] = {p0.x, p0.y, p0.z, p0.w, p1.x, p1.y, p1.z, p1.w};
        split8(vv, &bh[c], &bl[c]);
    }
#pragma unroll
    for (int c = 0; c < 2; ++c) {           // m split loaded directly
        const int ch0 = c * 32 + quad * 8;
        bh[2 + c] = *(const f16x8*)(mten + offP + ch0);
        bl[2 + c] = *(const f16x8*)(mten + S64P + offP + ch0);
    }

    floatx4 acc[4];
#pragma unroll
    for (int f = 0; f < 4; ++f) acc[f] = (floatx4){0.f, 0.f, 0.f, 0.f};
#pragma unroll
    for (int c = 0; c < 4; ++c)
#pragma unroll
        for (int f = 0; f < 4; ++f) {
            acc[f] = __builtin_amdgcn_mfma_f32_16x16x32_f16(wh[c][f], bh[c], acc[f], 0, 0, 0);
            acc[f] = __builtin_amdgcn_mfma_f32_16x16x32_f16(wh[c][f], bl[c], acc[f], 0, 0, 0);
            acc[f] = __builtin_amdgcn_mfma_f32_16x16x32_f16(wl[c][f], bh[c], acc[f], 0, 0, 0);
        }

#pragma unroll
    for (int f = 0; f < 4; ++f) {
        const int co = f * 16 + quad * 4;
        float4 ov = *(const float4*)(oten + offU + co);
        float hv[4];
        hv[0] = ov.x * tanhf(acc[f][0] + bias[co + 0]);
        hv[1] = ov.y * tanhf(acc[f][1] + bias[co + 1]);
        hv[2] = ov.z * tanhf(acc[f][2] + bias[co + 2]);
        hv[3] = ov.w * tanhf(acc[f][3] + bias[co + 3]);
        split_st4(houtp + offP + co, S64P, hv);
    }
}

// ---------------------------------------------------------------------------
// Gates: A/B split-unpadded in; h/m split-padded in; c fp32 in.
// out: r,xr,z,xz,o fp32 unpadded; rc,xm split padded. 4 ch per thread.
// ---------------------------------------------------------------------------
__global__ __launch_bounds__(256) void gates_cl(
    const _Float16* __restrict__ A, const _Float16* __restrict__ Bm,
    const _Float16* __restrict__ h, const _Float16* __restrict__ m,
    const float* __restrict__ c,
    const float* __restrict__ td_h, const float* __restrict__ td_m,
    const float* __restrict__ tg,
    float* r, float* xr, float* z, float* xz, float* o,
    _Float16* rc, _Float16* xm)
{
    const int i  = blockIdx.x * 256 + threadIdx.x;     // 262144 total
    const int ch = (i & 15) * 4;
    const long px = (i >> 4) & 4095;
    const int b  = i >> 16;
    const int y = (int)(px >> 6), xx = (int)(px & 63);
    const long pxP  = (long)(y + 1) * ROW + xx + 1;
    const long offU = ((long)b * HWN + px) * 64 + ch;
    const long offP = ((long)b * PXP + pxP) * 64 + ch;
    const long offA = ((long)b * HWN + px) * 192 + ch;
    const long offB = ((long)b * HWN + px) * 128 + ch;
    const long PSA = (long)Bn * HWN * 192, PSB = (long)Bn * HWN * 128;

    float Ar[4], Az[4], Ao[4], Br[4], Bz[4], hv[4], mv[4];
    rec4(A + offA, PSA, Ar);
    rec4(A + offA + 64, PSA, Az);
    rec4(A + offA + 128, PSA, Ao);
    rec4(Bm + offB, PSB, Br);
    rec4(Bm + offB + 64, PSB, Bz);
    rec4(h + offP, S64P, hv);
    rec4(m + offP, S64P, mv);
    float4 cv4 = *(const float4*)(c + offU);
    const float* cp = (const float*)&cv4;

    float rv[4], zv[4], ov[4], xrv[4], xzv[4], rcv[4], xmv[4];
#pragma unroll
    for (int j = 0; j < 4; ++j) {
        const float g  = sigmoidf_(tg[ch + j]);
        const float dh = expf(-td_h[ch + j]);
        const float dm = expf(-td_m[ch + j]);
        rv[j]  = sigmoidf_(Ar[j] * g + hv[j] * dh);
        zv[j]  = sigmoidf_(Az[j] * g + hv[j] * dh);
        ov[j]  = sigmoidf_(Ao[j]);
        xrv[j] = sigmoidf_(Br[j] * g + mv[j] * dm);
        xzv[j] = sigmoidf_(Bz[j] * g + mv[j] * dm);
        rcv[j] = rv[j] * cp[j];
        xmv[j] = xrv[j] * mv[j];
    }
    *(float4*)(r  + offU) = *(float4*)rv;
    *(float4*)(xr + offU) = *(float4*)xrv;
    *(float4*)(z  + offU) = *(float4*)zv;
    *(float4*)(xz + offU) = *(float4*)xzv;
    *(float4*)(o  + offU) = *(float4*)ov;
    split_st4(rc + offP, S64P, rcv);
    split_st4(xm + offP, S64P, xmv);
}

// ---------------------------------------------------------------------------
__global__ __launch_bounds__(256) void logits_part(
    const float* __restrict__ q, const float* __restrict__ k, float* __restrict__ part)
{
    __shared__ float qs[64][66], ks[64][66];
    const int tid = threadIdx.x;
    const int b = blockIdx.x, kc = blockIdx.y;
    const int cqq = tid >> 4, ckq = tid & 15;
    float pacc[4][4];
#pragma unroll
    for (int u = 0; u < 4; ++u)
#pragma unroll
        for (int v = 0; v < 4; ++v) pacc[u][v] = 0.f;

    for (int sub = 0; sub < 4; ++sub) {
        const int px0 = kc * 256 + sub * 64;
        __syncthreads();
#pragma unroll
        for (int rr = 0; rr < 16; ++rr) {
            const int idx = rr * 256 + tid;
            const int chh = idx >> 6, pxo = idx & 63;
            qs[chh][pxo] = q[((long)b * 64 + chh) * HWN + px0 + pxo];
            ks[chh][pxo] = k[((long)b * 64 + chh) * HWN + px0 + pxo];
        }
        __syncthreads();
        for (int p = 0; p < 64; ++p) {
            float qv[4], kv[4];
#pragma unroll
            for (int u = 0; u < 4; ++u) { qv[u] = qs[cqq + 16 * u][p]; kv[u] = ks[ckq + 16 * u][p]; }
#pragma unroll
            for (int u = 0; u < 4; ++u)
#pragma unroll
                for (int v = 0; v < 4; ++v) pacc[u][v] = fmaf(qv[u], kv[v], pacc[u][v]);
        }
    }
#pragma unroll
    for (int u = 0; u < 4; ++u)
#pragma unroll
        for (int v = 0; v < 4; ++v)
            part[(((long)b * 16 + kc) * 64 + cqq + 16 * u) * 64 + ckq + 16 * v] = pacc[u][v];
}

__global__ void reduce_softmax(const float* __restrict__ part, float* __restrict__ attn)
{
    const int row = blockIdx.x;
    const int b = row >> 6, cq = row & 63;
    const int lane = threadIdx.x;
    float s = 0.f;
#pragma unroll
    for (int kc = 0; kc < 16; ++kc)
        s += part[(((long)b * 16 + kc) * 64 + cq) * 64 + lane];
    float v = s * (1.f / 64.f);
    float mx = v;
    for (int off = 32; off; off >>= 1) mx = fmaxf(mx, __shfl_xor(mx, off));
    float e = expf(v - mx);
    float sum = e;
    for (int off = 32; off; off >>= 1) sum += __shfl_xor(sum, off);
    attn[row * 64 + lane] = e / sum;
}

// out[b,t,c,n] = sum_d attn[b,c,d] * v[t,b,n,d]  (v split-f16 padded cl)
__global__ __launch_bounds__(256) void out_cl(
    const float* __restrict__ attn, const _Float16* __restrict__ hs,
    float* __restrict__ outp)
{
    __shared__ __align__(16) float att_t[64][8];
    const int bt = blockIdx.x;
    const int b = bt >> 3, t = bt & 7;
    const int c0 = blockIdx.z * 8;
    const int tid = threadIdx.x;
    for (int i = tid; i < 512; i += 256) {
        int d = i >> 3, j = i & 7;
        att_t[d][j] = attn[(b * 64 + c0 + j) * 64 + d];
    }
    __syncthreads();

    const long px = blockIdx.y * 256 + tid;
    const int y = (int)(px >> 6), xx = (int)(px & 63);
    const long pxP = (long)(y + 1) * ROW + xx + 1;
    const _Float16* vb = hs + (long)t * 2 * S64P + ((long)b * PXP + pxP) * 64;

    float acc[8];
#pragma unroll
    for (int j = 0; j < 8; ++j) acc[j] = 0.f;
#pragma unroll 2
    for (int dg = 0; dg < 8; ++dg) {
        f16x8 hv = *(const f16x8*)(vb + dg * 8);
        f16x8 lv = *(const f16x8*)(vb + S64P + dg * 8);
#pragma unroll
        for (int j8 = 0; j8 < 8; ++j8) {
            const float vv = (float)hv[j8] + (float)lv[j8];
            const float4 a0 = *(const float4*)&att_t[dg * 8 + j8][0];
            const float4 a1 = *(const float4*)&att_t[dg * 8 + j8][4];
            acc[0] = fmaf(vv, a0.x, acc[0]); acc[1] = fmaf(vv, a0.y, acc[1]);
            acc[2] = fmaf(vv, a0.z, acc[2]); acc[3] = fmaf(vv, a0.w, acc[3]);
            acc[4] = fmaf(vv, a1.x, acc[4]); acc[5] = fmaf(vv, a1.y, acc[5]);
            acc[6] = fmaf(vv, a1.z, acc[6]); acc[7] = fmaf(vv, a1.w, acc[7]);
        }
    }
    const long ob = ((long)(b * 8 + t) * 64 + c0) * HWN + px;
#pragma unroll
    for (int j = 0; j < 8; ++j) outp[ob + (long)j * HWN] = acc[j];
}

// ---------------------------------------------------------------------------
extern "C" void kernel_launch(void* const* d_in, const int* in_sizes, int n_in,
                              void* d_out, int out_size, void* d_ws, size_t ws_size,
                              hipStream_t stream)
{
    const float* x = (const float*)d_in[0];
    const float* w_rzo[2] = {(const float*)d_in[1],  (const float*)d_in[12]};
    const float* b_rzo[2] = {(const float*)d_in[2],  (const float*)d_in[13]};
    const float* w_rz[2]  = {(const float*)d_in[3],  (const float*)d_in[14]};
    const float* b_rz[2]  = {(const float*)d_in[4],  (const float*)d_in[15]};
    const float* w_h[2]   = {(const float*)d_in[5],  (const float*)d_in[16]};
    const float* b_h[2]   = {(const float*)d_in[6],  (const float*)d_in[17]};
    const float* w_o[2]   = {(const float*)d_in[7],  (const float*)d_in[18]};
    const float* b_o[2]   = {(const float*)d_in[8],  (const float*)d_in[19]};
    const float* td_h[2]  = {(const float*)d_in[9],  (const float*)d_in[20]};
    const float* td_m[2]  = {(const float*)d_in[10], (const float*)d_in[21]};
    const float* tg[2]    = {(const float*)d_in[11], (const float*)d_in[22]};

    // ---- padded split-f16 region (memset 0 each call) ----
    _Float16* xcl = (_Float16*)d_ws;                 // 8t x 2 x SxP
    _Float16* h0  = xcl + (size_t)Tn * 2 * SxP;
    _Float16* m0  = h0  + 2 * S64P;
    _Float16* m1  = m0  + 2 * S64P;
    _Float16* rcb = m1  + 2 * S64P;
    _Float16* xmb = rcb + 2 * S64P;
    _Float16* hs  = xmb + 2 * S64P;                  // 8 x 2 x S64P
    _Float16* padEnd = hs + (size_t)Tn * 2 * S64P;
    const size_t padded_bytes = (char*)padEnd - (char*)d_ws;

    // ---- fp32 unpadded pointwise tensors ----
    float* c0  = (float*)padEnd;
    float* c1  = c0 + S64u;
    float* zb  = c1 + S64u;
    float* xzb = zb + S64u;
    float* ogb = xzb + S64u;
    float* rb  = ogb + S64u;
    float* xrb = rb + S64u;
    // ---- split-f16 unpadded conv outputs ----
    _Float16* A_cl = (_Float16*)(xrb + S64u);        // 2 x 4 x 4096 x 192
    _Float16* B_cl = A_cl + (size_t)2 * Bn * HWN * 192;
    _Float16* wA0 = B_cl + (size_t)2 * Bn * HWN * 128;
    _Float16* wB0 = wA0 + 331776;
    _Float16* wH0 = wB0 + 221184;
    _Float16* wA1 = wH0 + 110592;
    _Float16* wB1 = wA1 + 442368;
    _Float16* wH1 = wB1 + 294912;
    _Float16* wO0 = wH1 + 147456;
    _Float16* wO1 = wO0 + 16384;
    // q/k/partials/attn overlay A_cl (dead after last gates)
    float* qbuf  = (float*)A_cl;
    float* kbuf  = qbuf + S64u;
    float* partb = kbuf + S64u;
    float* attnb = partb + (size_t)Bn * 16 * 64 * 64;

    hipMemsetAsync(d_ws, 0, padded_bytes, stream);              // borders + init states
    hipMemsetAsync(c0, 0, 2 * S64u * sizeof(float), stream);    // c0, c1

    prep_x_kernel<<<512, 256, 0, stream>>>(x, xcl);
    prep_w_kernel<<<128, 256, 0, stream>>>(w_rzo[0], wA0, 80, 16, 32, 192, 3, 9);
    prep_w_kernel<<<128, 256, 0, stream>>>(w_rz[0],  wB0, 80, 16, 32, 128, 3, 9);
    prep_w_kernel<<<128, 256, 0, stream>>>(w_h[0],   wH0, 80, 16, 32, 64, 3, 9);
    prep_w_kernel<<<128, 256, 0, stream>>>(w_rzo[1], wA1, 128, 64, 64, 192, 4, 9);
    prep_w_kernel<<<128, 256, 0, stream>>>(w_rz[1],  wB1, 128, 64, 64, 128, 4, 9);
    prep_w_kernel<<<128, 256, 0, stream>>>(w_h[1],   wH1, 128, 64, 64, 64, 4, 9);
    prep_w_kernel<<<64, 256, 0, stream>>>(w_o[0], wO0, 128, 64, 64, 64, 4, 1);
    prep_w_kernel<<<64, 256, 0, stream>>>(w_o[1], wO1, 128, 64, 64, 64, 4, 1);

    for (int t = 0; t < Tn; ++t) {
        const _Float16* xt = xcl + (size_t)t * 2 * SxP;
        const _Float16* h1prev = (t == 0) ? (hs + (size_t)7 * 2 * S64P)
                                          : (hs + (size_t)(t - 1) * 2 * S64P);
        _Float16* h1out = hs + (size_t)t * 2 * S64P;

        // ---------- layer 0: inp=x_t, h=h0, c=c0, m_in=m1 -> m_out=m0 ----------
        conv3m<0, 2><<<dim3(16, 10, 4), 256, 0, stream>>>(
            xt, 32, SxP, h0, m1, S64P, 1, 3,
            wA0, b_rzo[0], A_cl, 192, 12,
            wB0, b_rz[0],  B_cl, 128, 8, 6,
            nullptr, nullptr, nullptr, nullptr, nullptr, nullptr,
            nullptr, nullptr, nullptr, nullptr, 0);
        gates_cl<<<1024, 256, 0, stream>>>(A_cl, B_cl, h0, m1, c0,
            td_h[0], td_m[0], tg[0], rb, xrb, zb, xzb, ogb, rcb, xmb);
        conv3m<1, 1><<<dim3(16, 4, 8), 256, 0, stream>>>(
            xt, 32, SxP, rcb, xmb, S64P, 1, 3,
            wH0, b_h[0], nullptr, 64, 4,
            wH0, b_h[0], nullptr, 64, 4, 0,
            zb, xzb, c0, m1, c0, m0, rb, xrb, qbuf, kbuf, 0);
        conv1x1m<<<dim3(64, 4), 256, 0, stream>>>(c0, m0, ogb, wO0, b_o[0], h0);

        // ---------- layer 1: inp=h0, h=hs[t-1], c=c1, m_in=m0 -> m_out=m1 -------
        conv3m<0, 2><<<dim3(16, 10, 4), 256, 0, stream>>>(
            h0, 64, S64P, h1prev, m0, S64P, 2, 4,
            wA1, b_rzo[1], A_cl, 192, 12,
            wB1, b_rz[1],  B_cl, 128, 8, 6,
            nullptr, nullptr, nullptr, nullptr, nullptr, nullptr,
            nullptr, nullptr, nullptr, nullptr, 0);
        gates_cl<<<1024, 256, 0, stream>>>(A_cl, B_cl, h1prev, m0, c1,
            td_h[1], td_m[1], tg[1], rb, xrb, zb, xzb, ogb, rcb, xmb);
        conv3m<1, 1><<<dim3(16, 4, 8), 256, 0, stream>>>(
            h0, 64, S64P, rcb, xmb, S64P, 2, 4,
            wH1, b_h[1], nullptr, 64, 4,
            wH1, b_h[1], nullptr, 64, 4, 0,
            zb, xzb, c1, m0, c1, m1, rb, xrb, qbuf, kbuf, (t == Tn - 1) ? 1 : 0);
        conv1x1m<<<dim3(64, 4), 256, 0, stream>>>(c1, m1, ogb, wO1, b_o[1], h1out);
    }

    // ---------- attention ----------
    logits_part<<<dim3(4, 16), 256, 0, stream>>>(qbuf, kbuf, partb);
    reduce_softmax<<<256, 64, 0, stream>>>(partb, attnb);
    out_cl<<<dim3(32, 16, 8), 256, 0, stream>>>(attnb, hs, (float*)d_out);
}

// Round 8
// 1563.517 us; speedup vs baseline: 19.8252x; 19.8252x over previous
//
#include <hip/hip_runtime.h>
#include <math.h>

#define HWN 4096
#define Bn 4
#define Tn 8

typedef __attribute__((ext_vector_type(8))) _Float16 f16x8;
typedef __attribute__((ext_vector_type(4))) float floatx4;

__device__ __forceinline__ float sigmoidf_(float v) { return 1.f / (1.f + expf(-v)); }

// split 8 fp32 -> f16 hi/lo vectors (value = hi + lo, ~22-bit effective)
__device__ __forceinline__ void split8(const float* vv, f16x8* hi, f16x8* lo) {
#pragma unroll
    for (int j = 0; j < 8; ++j) {
        _Float16 h = (_Float16)vv[j];
        (*hi)[j] = h;
        (*lo)[j] = (_Float16)(vv[j] - (float)h);
    }
}

// ---------------------------------------------------------------------------
// Weight prep: fp32 [Cout][Ctot][KK] -> A-fragment-swizzled split-f16:
// [plane][kk][chunk][cog][lane][j]; lane frag = 8 contiguous f16 (dwordx4).
// A-frag (16x16x32): A[m=lane&15][k=(lane>>4)*8+j].
// ---------------------------------------------------------------------------
__global__ __launch_bounds__(256) void prep_w_kernel(
    const float* __restrict__ W, _Float16* __restrict__ dst,
    int Ctot, int Cout, int nch, int KK)
{
    const int ncog = Cout >> 4;
    const long total = (long)KK * nch * ncog * 512;
    for (long i = (long)blockIdx.x * 256 + threadIdx.x; i < total;
         i += (long)gridDim.x * 256) {
        int j    = (int)(i & 7);
        int lane = (int)((i >> 3) & 63);
        long r   = i >> 9;
        int f = (int)(r % ncog); r /= ncog;
        int c = (int)(r % nch);  r /= nch;
        int kk = (int)r;
        int co = f * 16 + (lane & 15);
        int ci = c * 32 + (lane >> 4) * 8 + j;
        float v = (ci < Ctot) ? W[((long)co * Ctot + ci) * KK + kk] : 0.f;
        _Float16 hi = (_Float16)v;
        dst[i]         = hi;
        dst[total + i] = (_Float16)(v - (float)hi);
    }
}

// x fp32 [b][t][16][4096] -> x_cl fp32 [t][b][px][16]
__global__ __launch_bounds__(256) void prep_x_kernel(
    const float* __restrict__ x, float* __restrict__ xcl)
{
    const int i = blockIdx.x * 256 + threadIdx.x;     // 131072 total
    const int px = i & 4095;
    const int t  = (i >> 12) & 7;
    const int b  = i >> 15;
    float* d = xcl + (((long)t * Bn + b) * HWN + px) * 16;
#pragma unroll
    for (int ch = 0; ch < 16; ++ch)
        d[ch] = x[((long)(b * 8 + t) * 16 + ch) * HWN + px];
}

// ---------------------------------------------------------------------------
// MFMA implicit-GEMM 3x3 SAME conv, fp32 channels-last activations, hi/lo
// f16 split during LDS staging (round-2/5/6-verified numerics).
// NF = cout 16-frags per wave (wave covers NF*16 couts); NG = pixel-row
// groups per wave (wave covers NG*16 px). Block = 4 waves stacked in rows:
// tile = NF*16 couts x (16 cols x 4*NG rows). LDS [4*NG+2][18][2][40].
// Per-CU LDS-port demand vs MFMA: (4*NG*2*12)/(NF*NG*3*4.8) = 1.67x @ NF=4.
// EPI=0: plain conv, merged A/B dispatch (which = blockIdx.y >= nA).
// EPI=1: H-conv + tanh + state update (+ q/k on last cell); which=z>>2.
// ---------------------------------------------------------------------------
template<int EPI, int NF, int NG>
__global__ __launch_bounds__(256) void conv3m(
    const float* __restrict__ in1, int C1,
    const float* __restrict__ in2a, const float* __restrict__ in2b,
    int Ctot, int nch,
    const _Float16* __restrict__ wA, const float* __restrict__ biasA,
    float* outA, int CoutA, int ncogA,
    const _Float16* __restrict__ wB, const float* __restrict__ biasB,
    float* outB, int CoutB, int ncogB, int nA,
    const float* zA, const float* zB,
    const float* sA, const float* sB,
    const float* rten, const float* xrten,
    float* qout, float* kout, int last)
{
    __shared__ __align__(16) _Float16 ldsB[4 * NG + 2][18][2][40];

    const int tid = threadIdx.x;
    const int ty0 = (blockIdx.x >> 2) * (4 * NG);
    const int tx0 = (blockIdx.x & 3) * 16;
    const int b   = blockIdx.z & 3;
    const int which = (EPI == 1) ? (int)(blockIdx.z >> 2)
                                 : (blockIdx.y >= (unsigned)nA ? 1 : 0);

    const float*    in2  = which ? in2b : in2a;
    const _Float16* Wf   = which ? wB : wA;
    const float*    bias = which ? biasB : biasA;
    float*          outp = which ? outB : outA;
    const int Cout = which ? CoutB : CoutA;
    const int ncog = which ? ncogB : ncogA;
    const int cog0 = (EPI == 1) ? blockIdx.y * NF
                   : (which ? (blockIdx.y - nA) * NF : blockIdx.y * NF);
    const int co0  = cog0 * 16;

    const int lane = tid & 63, wv = tid >> 6, tl = lane & 15, quad = lane >> 4;
    const int C2 = Ctot - C1;
    const long wplane = (long)9 * nch * ncog * 512;
    const float* in1b  = in1 + (long)b * HWN * C1;
    const float* in2bb = in2 + (long)b * HWN * C2;

    floatx4 acc[NF][NG];
#pragma unroll
    for (int f = 0; f < NF; ++f)
#pragma unroll
        for (int g = 0; g < NG; ++g) acc[f][g] = (floatx4){0.f, 0.f, 0.f, 0.f};

    const int UNITS = (4 * NG + 2) * 18 * 4;

    for (int c = 0; c < nch; ++c) {
        __syncthreads();
        const int c0 = c * 32;
        for (int i = tid; i < UNITS; i += 256) {
            const int pxh = i >> 2, cig = i & 3;
            const int yh = pxh / 18, xh = pxh - yh * 18;
            const int y = ty0 + yh - 1, x = tx0 + xh - 1;
            const int ch = c0 + cig * 8;
            f16x8 vh = {0, 0, 0, 0, 0, 0, 0, 0};
            f16x8 vl = {0, 0, 0, 0, 0, 0, 0, 0};
            if (ch < Ctot && (unsigned)y < 64u && (unsigned)x < 64u) {
                const float* src; long off;
                if (ch < C1) { src = in1b;  off = (long)(y * 64 + x) * C1 + ch; }
                else         { src = in2bb; off = (long)(y * 64 + x) * C2 + ch - C1; }
                float4 a  = *(const float4*)(src + off);
                float4 b4 = *(const float4*)(src + off + 4);
                float vv[8] = {a.x, a.y, a.z, a.w, b4.x, b4.y, b4.z, b4.w};
                split8(vv, &vh, &vl);
            }
            *(f16x8*)&ldsB[yh][xh][0][cig * 8] = vh;
            *(f16x8*)&ldsB[yh][xh][1][cig * 8] = vl;
        }
        __syncthreads();

        // weight double-buffer across kk
        f16x8 wh[2][NF], wl[2][NF];
        {
            const long wo0 = ((long)(0 * nch + c) * ncog + cog0) * 512 + lane * 8;
#pragma unroll
            for (int f = 0; f < NF; ++f) {
                wh[0][f] = *(const f16x8*)(Wf + wo0 + (long)f * 512);
                wl[0][f] = *(const f16x8*)(Wf + wplane + wo0 + (long)f * 512);
            }
        }
#pragma unroll
        for (int kk = 0; kk < 9; ++kk) {
            const int cur = kk & 1, nxt = cur ^ 1;
            if (kk < 8) {
                const long wo = ((long)((kk + 1) * nch + c) * ncog + cog0) * 512 + lane * 8;
#pragma unroll
                for (int f = 0; f < NF; ++f) {
                    wh[nxt][f] = *(const f16x8*)(Wf + wo + (long)f * 512);
                    wl[nxt][f] = *(const f16x8*)(Wf + wplane + wo + (long)f * 512);
                }
            }
            const int ky = kk / 3, kx = kk - ky * 3;
            f16x8 bh[NG], bl[NG];
#pragma unroll
            for (int g = 0; g < NG; ++g) {
                const _Float16* pB = &ldsB[wv * NG + g + ky][tl + kx][0][quad * 8];
                bh[g] = *(const f16x8*)pB;
                bl[g] = *(const f16x8*)(pB + 40);
            }
            // product-pass order: NF*NG independent MFMAs between acc reuses
#pragma unroll
            for (int f = 0; f < NF; ++f)
#pragma unroll
                for (int g = 0; g < NG; ++g)
                    acc[f][g] = __builtin_amdgcn_mfma_f32_16x16x32_f16(wh[cur][f], bh[g], acc[f][g], 0, 0, 0);
#pragma unroll
            for (int f = 0; f < NF; ++f)
#pragma unroll
                for (int g = 0; g < NG; ++g)
                    acc[f][g] = __builtin_amdgcn_mfma_f32_16x16x32_f16(wh[cur][f], bl[g], acc[f][g], 0, 0, 0);
#pragma unroll
            for (int f = 0; f < NF; ++f)
#pragma unroll
                for (int g = 0; g < NG; ++g)
                    acc[f][g] = __builtin_amdgcn_mfma_f32_16x16x32_f16(wl[cur][f], bh[g], acc[f][g], 0, 0, 0);
        }
    }

    // epilogue: C/D layout col(px)=lane&15, row(co)=quad*4+reg
    if (EPI == 0) {
        const long obb = (long)b * HWN * Cout;
#pragma unroll
        for (int f = 0; f < NF; ++f) {
            const int co = co0 + f * 16 + quad * 4;
#pragma unroll
            for (int g = 0; g < NG; ++g) {
                const long px = (long)(ty0 + wv * NG + g) * 64 + tx0 + tl;
                float4 v;
                v.x = acc[f][g][0] + bias[co + 0];
                v.y = acc[f][g][1] + bias[co + 1];
                v.z = acc[f][g][2] + bias[co + 2];
                v.w = acc[f][g][3] + bias[co + 3];
                *(float4*)(outp + obb + px * Cout + co) = v;
            }
        }
    } else {
        const float* zt = which ? zB : zA;
        const float* st = which ? sB : sA;
        float* qk = which ? kout : qout;
#pragma unroll
        for (int f = 0; f < NF; ++f) {
            const int co = co0 + f * 16 + quad * 4;
#pragma unroll
            for (int g = 0; g < NG; ++g) {
                const long px = (long)(ty0 + wv * NG + g) * 64 + tx0 + tl;
                const long off = (long)b * HWN * 64 + px * 64 + co;
                float4 zv = *(const float4*)(zt + off);
                float4 sv = *(const float4*)(st + off);
                float gv[4], cn[4];
                gv[0] = tanhf(acc[f][g][0] + bias[co + 0]);
                gv[1] = tanhf(acc[f][g][1] + bias[co + 1]);
                gv[2] = tanhf(acc[f][g][2] + bias[co + 2]);
                gv[3] = tanhf(acc[f][g][3] + bias[co + 3]);
                cn[0] = zv.x * sv.x + (1.f - zv.x) * gv[0];
                cn[1] = zv.y * sv.y + (1.f - zv.y) * gv[1];
                cn[2] = zv.z * sv.z + (1.f - zv.z) * gv[2];
                cn[3] = zv.w * sv.w + (1.f - zv.w) * gv[3];
                *(float4*)(outp + off) = *(float4*)cn;
                if (last) {
                    float4 rv = *(const float4*)(rten + off);
                    float4 xv = *(const float4*)(xrten + off);
                    qk[((long)(b * 64) + co + 0) * HWN + px] = 0.25f * (rv.x + xv.x + cn[0] + gv[0]);
                    qk[((long)(b * 64) + co + 1) * HWN + px] = 0.25f * (rv.y + xv.y + cn[1] + gv[1]);
                    qk[((long)(b * 64) + co + 2) * HWN + px] = 0.25f * (rv.z + xv.z + cn[2] + gv[2]);
                    qk[((long)(b * 64) + co + 3) * HWN + px] = 0.25f * (rv.w + xv.w + cn[3] + gv[3]);
                }
            }
        }
    }
}

// ---------------------------------------------------------------------------
// 1x1 conv (MFMA) over concat([c,m]) fp32-cl -> h = o * tanh(conv + bias).
// grid (64, B) = 256 blocks; block = 4 waves; wave = 16 px x 64 co.
// ---------------------------------------------------------------------------
__global__ __launch_bounds__(256) void conv1x1m(
    const float* __restrict__ cten, const float* __restrict__ mten,
    const float* __restrict__ oten,
    const _Float16* __restrict__ W, const float* __restrict__ bias,
    float* houtp)
{
    const int tid = threadIdx.x;
    const int lane = tid & 63, wv = tid >> 6, tl = lane & 15, quad = lane >> 4;
    const int b = blockIdx.y;
    const int px = blockIdx.x * 64 + wv * 16 + tl;
    const long bb = (long)b * HWN * 64;

    f16x8 wh[4][4], wl[4][4];
#pragma unroll
    for (int c = 0; c < 4; ++c)
#pragma unroll
        for (int f = 0; f < 4; ++f) {
            const long wo = (long)(c * 4 + f) * 512 + lane * 8;
            wh[c][f] = *(const f16x8*)(W + wo);
            wl[c][f] = *(const f16x8*)(W + 8192 + wo);
        }
    f16x8 bh[4], bl[4];
#pragma unroll
    for (int c = 0; c < 4; ++c) {
        const float* src = (c < 2) ? cten : mten;
        const int ch0 = (c & 1) * 32 + quad * 8;
        const long off = bb + (long)px * 64 + ch0;
        float4 p0 = *(const float4*)(src + off);
        float4 p1 = *(const float4*)(src + off + 4);
        float vv[8] = {p0.x, p0.y, p0.z, p0.w, p1.x, p1.y, p1.z, p1.w};
        split8(vv, &bh[c], &bl[c]);
    }

    floatx4 acc[4];
#pragma unroll
    for (int f = 0; f < 4; ++f) acc[f] = (floatx4){0.f, 0.f, 0.f, 0.f};
#pragma unroll
    for (int c = 0; c < 4; ++c)
#pragma unroll
        for (int f = 0; f < 4; ++f) {
            acc[f] = __builtin_amdgcn_mfma_f32_16x16x32_f16(wh[c][f], bh[c], acc[f], 0, 0, 0);
            acc[f] = __builtin_amdgcn_mfma_f32_16x16x32_f16(wh[c][f], bl[c], acc[f], 0, 0, 0);
            acc[f] = __builtin_amdgcn_mfma_f32_16x16x32_f16(wl[c][f], bh[c], acc[f], 0, 0, 0);
        }

#pragma unroll
    for (int f = 0; f < 4; ++f) {
        const int co = f * 16 + quad * 4;
        const long off = bb + (long)px * 64 + co;
        float4 ov = *(const float4*)(oten + off);
        float4 hv;
        hv.x = ov.x * tanhf(acc[f][0] + bias[co + 0]);
        hv.y = ov.y * tanhf(acc[f][1] + bias[co + 1]);
        hv.z = ov.z * tanhf(acc[f][2] + bias[co + 2]);
        hv.w = ov.w * tanhf(acc[f][3] + bias[co + 3]);
        *(float4*)(houtp + off) = hv;
    }
}

// ---------------------------------------------------------------------------
// Gates: r,z,o,xr,xz + rc, xm — fp32 channels-last, 4 ch per thread.
// ---------------------------------------------------------------------------
__global__ __launch_bounds__(256) void gates_cl(
    const float* __restrict__ A, const float* __restrict__ Bm,
    const float* __restrict__ h, const float* __restrict__ m,
    const float* __restrict__ c,
    const float* __restrict__ td_h, const float* __restrict__ td_m,
    const float* __restrict__ tg,
    float* r, float* xr, float* z, float* xz,
    float* o, float* rc, float* xm)
{
    const int i  = blockIdx.x * 256 + threadIdx.x;     // 262144 total
    const int ch = (i & 15) * 4;
    const long px = (i >> 4) & 4095;
    const int b  = i >> 16;
    const long b64  = ((long)b * HWN + px) * 64 + ch;
    const long b192 = ((long)b * HWN + px) * 192 + ch;
    const long b128 = ((long)b * HWN + px) * 128 + ch;

    float4 Ar = *(const float4*)(A + b192);
    float4 Az = *(const float4*)(A + b192 + 64);
    float4 Ao = *(const float4*)(A + b192 + 128);
    float4 Br = *(const float4*)(Bm + b128);
    float4 Bz = *(const float4*)(Bm + b128 + 64);
    float4 hv = *(const float4*)(h + b64);
    float4 mv = *(const float4*)(m + b64);
    float4 cv = *(const float4*)(c + b64);

    float rv[4], zv[4], ov[4], xrv[4], xzv[4], rcv[4], xmv[4];
    const float* Arp = (const float*)&Ar; const float* Azp = (const float*)&Az;
    const float* Aop = (const float*)&Ao; const float* Brp = (const float*)&Br;
    const float* Bzp = (const float*)&Bz; const float* hp = (const float*)&hv;
    const float* mp = (const float*)&mv;  const float* cp = (const float*)&cv;
#pragma unroll
    for (int j = 0; j < 4; ++j) {
        const float g  = sigmoidf_(tg[ch + j]);
        const float dh = expf(-td_h[ch + j]);
        const float dm = expf(-td_m[ch + j]);
        rv[j]  = sigmoidf_(Arp[j] * g + hp[j] * dh);
        zv[j]  = sigmoidf_(Azp[j] * g + hp[j] * dh);
        ov[j]  = sigmoidf_(Aop[j]);
        xrv[j] = sigmoidf_(Brp[j] * g + mp[j] * dm);
        xzv[j] = sigmoidf_(Bzp[j] * g + mp[j] * dm);
        rcv[j] = rv[j] * cp[j];
        xmv[j] = xrv[j] * mp[j];
    }
    *(float4*)(r  + b64) = *(float4*)rv;
    *(float4*)(xr + b64) = *(float4*)xrv;
    *(float4*)(z  + b64) = *(float4*)zv;
    *(float4*)(xz + b64) = *(float4*)xzv;
    *(float4*)(o  + b64) = *(float4*)ov;
    *(float4*)(rc + b64) = *(float4*)rcv;
    *(float4*)(xm + b64) = *(float4*)xmv;
}

// ---------------------------------------------------------------------------
// logits split-K: grid (b, 16 K-chunks of 256 px); partial C[64][64] each.
// ---------------------------------------------------------------------------
__global__ __launch_bounds__(256) void logits_part(
    const float* __restrict__ q, const float* __restrict__ k, float* __restrict__ part)
{
    __shared__ float qs[64][66], ks[64][66];
    const int tid = threadIdx.x;
    const int b = blockIdx.x, kc = blockIdx.y;
    const int cqq = tid >> 4, ckq = tid & 15;
    float pacc[4][4];
#pragma unroll
    for (int u = 0; u < 4; ++u)
#pragma unroll
        for (int v = 0; v < 4; ++v) pacc[u][v] = 0.f;

    for (int sub = 0; sub < 4; ++sub) {
        const int px0 = kc * 256 + sub * 64;
        __syncthreads();
#pragma unroll
        for (int rr = 0; rr < 16; ++rr) {
            const int idx = rr * 256 + tid;
            const int chh = idx >> 6, pxo = idx & 63;
            qs[chh][pxo] = q[((long)b * 64 + chh) * HWN + px0 + pxo];
            ks[chh][pxo] = k[((long)b * 64 + chh) * HWN + px0 + pxo];
        }
        __syncthreads();
        for (int p = 0; p < 64; ++p) {
            float qv[4], kv[4];
#pragma unroll
            for (int u = 0; u < 4; ++u) { qv[u] = qs[cqq + 16 * u][p]; kv[u] = ks[ckq + 16 * u][p]; }
#pragma unroll
            for (int u = 0; u < 4; ++u)
#pragma unroll
                for (int v = 0; v < 4; ++v) pacc[u][v] = fmaf(qv[u], kv[v], pacc[u][v]);
        }
    }
#pragma unroll
    for (int u = 0; u < 4; ++u)
#pragma unroll
        for (int v = 0; v < 4; ++v)
            part[(((long)b * 16 + kc) * 64 + cqq + 16 * u) * 64 + ckq + 16 * v] = pacc[u][v];
}

// reduce 16 partials + softmax; one wave per (b,cq) row
__global__ void reduce_softmax(const float* __restrict__ part, float* __restrict__ attn)
{
    const int row = blockIdx.x;            // b*64 + cq
    const int b = row >> 6, cq = row & 63;
    const int lane = threadIdx.x;
    float s = 0.f;
#pragma unroll
    for (int kc = 0; kc < 16; ++kc)
        s += part[(((long)b * 16 + kc) * 64 + cq) * 64 + lane];
    float v = s * (1.f / 64.f);
    float mx = v;
    for (int off = 32; off; off >>= 1) mx = fmaxf(mx, __shfl_xor(mx, off));
    float e = expf(v - mx);
    float sum = e;
    for (int off = 32; off; off >>= 1) sum += __shfl_xor(sum, off);
    attn[row * 64 + lane] = e / sum;
}

// out[b,t,c,n] = sum_d attn[b,c,d] * v[t,b,n,d]   (v fp32 channels-last)
__global__ __launch_bounds__(256) void out_cl(
    const float* __restrict__ attn, const float* __restrict__ hs,
    float* __restrict__ outp)
{
    __shared__ __align__(16) float att_t[64][8];
    const int bt = blockIdx.x;
    const int b = bt >> 3, t = bt & 7;
    const int c0 = blockIdx.z * 8;
    const int tid = threadIdx.x;
    for (int i = tid; i < 512; i += 256) {
        int d = i >> 3, j = i & 7;
        att_t[d][j] = attn[(b * 64 + c0 + j) * 64 + d];
    }
    __syncthreads();

    const long px = blockIdx.y * 256 + tid;
    const long SLOT = (long)Bn * HWN * 64;
    const float* vb = hs + (long)t * SLOT + ((long)b * HWN + px) * 64;

    float acc[8];
#pragma unroll
    for (int j = 0; j < 8; ++j) acc[j] = 0.f;
#pragma unroll 4
    for (int dg = 0; dg < 16; ++dg) {
        float4 v4 = *(const float4*)(vb + dg * 4);
        const float* vp = (const float*)&v4;
#pragma unroll
        for (int j4 = 0; j4 < 4; ++j4) {
            const float vv = vp[j4];
            const float4 a0 = *(const float4*)&att_t[dg * 4 + j4][0];
            const float4 a1 = *(const float4*)&att_t[dg * 4 + j4][4];
            acc[0] = fmaf(vv, a0.x, acc[0]); acc[1] = fmaf(vv, a0.y, acc[1]);
            acc[2] = fmaf(vv, a0.z, acc[2]); acc[3] = fmaf(vv, a0.w, acc[3]);
            acc[4] = fmaf(vv, a1.x, acc[4]); acc[5] = fmaf(vv, a1.y, acc[5]);
            acc[6] = fmaf(vv, a1.z, acc[6]); acc[7] = fmaf(vv, a1.w, acc[7]);
        }
    }
    const long ob = ((long)(b * 8 + t) * 64 + c0) * HWN + px;
#pragma unroll
    for (int j = 0; j < 8; ++j) outp[ob + (long)j * HWN] = acc[j];
}

// ---------------------------------------------------------------------------
extern "C" void kernel_launch(void* const* d_in, const int* in_sizes, int n_in,
                              void* d_out, int out_size, void* d_ws, size_t ws_size,
                              hipStream_t stream)
{
    const float* x = (const float*)d_in[0];
    const float* w_rzo[2] = {(const float*)d_in[1],  (const float*)d_in[12]};
    const float* b_rzo[2] = {(const float*)d_in[2],  (const float*)d_in[13]};
    const float* w_rz[2]  = {(const float*)d_in[3],  (const float*)d_in[14]};
    const float* b_rz[2]  = {(const float*)d_in[4],  (const float*)d_in[15]};
    const float* w_h[2]   = {(const float*)d_in[5],  (const float*)d_in[16]};
    const float* b_h[2]   = {(const float*)d_in[6],  (const float*)d_in[17]};
    const float* w_o[2]   = {(const float*)d_in[7],  (const float*)d_in[18]};
    const float* b_o[2]   = {(const float*)d_in[8],  (const float*)d_in[19]};
    const float* td_h[2]  = {(const float*)d_in[9],  (const float*)d_in[20]};
    const float* td_m[2]  = {(const float*)d_in[10], (const float*)d_in[21]};
    const float* tg[2]    = {(const float*)d_in[11], (const float*)d_in[22]};

    // ---- workspace layout (fp32 channels-last activations) ----
    const size_t S64 = (size_t)Bn * HWN * 64;          // 1M floats = 4 MiB
    float* P = (float*)d_ws;
    float* h0    = P; P += S64;
    float* c0    = P; P += S64;
    float* m0    = P; P += S64;
    float* c1    = P; P += S64;
    float* m1    = P; P += S64;
    float* zslab = P; P += S64;                        // zeros; h1prev @ t=0
    float* A_cl  = P; P += (size_t)Bn * HWN * 192;     // 12 MiB
    float* B_cl  = P; P += (size_t)Bn * HWN * 128;     // 8 MiB
    float* rb    = P; P += S64;
    float* xrb   = P; P += S64;
    float* zb    = P; P += S64;
    float* xzb   = P; P += S64;
    float* ogb   = P; P += S64;
    float* rcb   = P; P += S64;
    float* xmb   = P; P += S64;
    float* hs    = P; P += (size_t)Tn * S64;           // 32 MiB
    float* x_cl  = P; P += (size_t)Tn * Bn * HWN * 16; // 8 MiB
    _Float16* wA0 = (_Float16*)P;
    _Float16* wB0 = wA0 + 331776;
    _Float16* wH0 = wB0 + 221184;
    _Float16* wA1 = wH0 + 110592;
    _Float16* wB1 = wA1 + 442368;
    _Float16* wH1 = wB1 + 294912;
    _Float16* wO0 = wH1 + 147456;
    _Float16* wO1 = wO0 + 16384;
    // q/k/partials/attn overlay A_cl (dead after last gates; logits run after)
    float* qbuf  = A_cl;
    float* kbuf  = qbuf + S64;                          // 4 MiB
    float* partb = kbuf + S64;                          // 1 MiB
    float* attnb = partb + (size_t)Bn * 16 * 64 * 64;   // 64 KiB

    hipMemsetAsync(h0, 0, 6 * S64 * sizeof(float), stream);

    prep_x_kernel<<<512, 256, 0, stream>>>(x, x_cl);
    prep_w_kernel<<<128, 256, 0, stream>>>(w_rzo[0], wA0, 80, 192, 3, 9);
    prep_w_kernel<<<128, 256, 0, stream>>>(w_rz[0],  wB0, 80, 128, 3, 9);
    prep_w_kernel<<<128, 256, 0, stream>>>(w_h[0],   wH0, 80,  64, 3, 9);
    prep_w_kernel<<<128, 256, 0, stream>>>(w_rzo[1], wA1, 128, 192, 4, 9);
    prep_w_kernel<<<128, 256, 0, stream>>>(w_rz[1],  wB1, 128, 128, 4, 9);
    prep_w_kernel<<<128, 256, 0, stream>>>(w_h[1],   wH1, 128, 64, 4, 9);
    prep_w_kernel<<<64, 256, 0, stream>>>(w_o[0], wO0, 128, 64, 4, 1);
    prep_w_kernel<<<64, 256, 0, stream>>>(w_o[1], wO1, 128, 64, 4, 1);

    for (int t = 0; t < Tn; ++t) {
        const float* xt = x_cl + (size_t)t * Bn * HWN * 16;
        const float* h1prev = (t == 0) ? zslab : (hs + (size_t)(t - 1) * S64);
        float* h1out = hs + (size_t)t * S64;

        // ---------- layer 0: inp=x_t, h=h0, c=c0, m_in=m1 -> m_out=m0 ----------
        conv3m<0, 4, 2><<<dim3(32, 5, 4), 256, 0, stream>>>(
            xt, 16, h0, m1, 80, 3,
            wA0, b_rzo[0], A_cl, 192, 12,
            wB0, b_rz[0],  B_cl, 128, 8, 3,
            nullptr, nullptr, nullptr, nullptr, nullptr, nullptr, nullptr, nullptr, 0);
        gates_cl<<<1024, 256, 0, stream>>>(A_cl, B_cl, h0, m1, c0,
            td_h[0], td_m[0], tg[0], rb, xrb, zb, xzb, ogb, rcb, xmb);
        conv3m<1, 4, 1><<<dim3(64, 1, 8), 256, 0, stream>>>(
            xt, 16, rcb, xmb, 80, 3,
            wH0, b_h[0], c0, 64, 4,
            wH0, b_h[0], m0, 64, 4, 0,
            zb, xzb, c0, m1, rb, xrb, qbuf, kbuf, 0);
        conv1x1m<<<dim3(64, 4), 256, 0, stream>>>(c0, m0, ogb, wO0, b_o[0], h0);

        // ---------- layer 1: inp=h0, h=hs[t-1], c=c1, m_in=m0 -> m_out=m1 -------
        conv3m<0, 4, 2><<<dim3(32, 5, 4), 256, 0, stream>>>(
            h0, 64, h1prev, m0, 128, 4,
            wA1, b_rzo[1], A_cl, 192, 12,
            wB1, b_rz[1],  B_cl, 128, 8, 3,
            nullptr, nullptr, nullptr, nullptr, nullptr, nullptr, nullptr, nullptr, 0);
        gates_cl<<<1024, 256, 0, stream>>>(A_cl, B_cl, h1prev, m0, c1,
            td_h[1], td_m[1], tg[1], rb, xrb, zb, xzb, ogb, rcb, xmb);
        conv3m<1, 4, 1><<<dim3(64, 1, 8), 256, 0, stream>>>(
            h0, 64, rcb, xmb, 128, 4,
            wH1, b_h[1], c1, 64, 4,
            wH1, b_h[1], m1, 64, 4, 0,
            zb, xzb, c1, m0, rb, xrb, qbuf, kbuf, (t == Tn - 1) ? 1 : 0);
        conv1x1m<<<dim3(64, 4), 256, 0, stream>>>(c1, m1, ogb, wO1, b_o[1], h1out);
    }

    // ---------- attention ----------
    logits_part<<<dim3(4, 16), 256, 0, stream>>>(qbuf, kbuf, partb);
    reduce_softmax<<<256, 64, 0, stream>>>(partb, attnb);
    out_cl<<<dim3(32, 16, 8), 256, 0, stream>>>(attnb, hs, (float*)d_out);
}